// Round 3
// baseline (86.539 us; speedup 1.0000x reference)
//
#include <hip/hip_runtime.h>

// input: (B=16, S=4096, C=128) fp32; shift: (B=16, T=2048) fp32
// out[b,t,c] = sum_s exp(-4*(shift[b,t]+s-t)^2) * input[b,s,c]
// exp(-4x^2) < 1e-85 for |x| >= 7  =>  16-wide window centered at t-shift is exact in fp32.
constexpr int B = 16;
constexpr int S = 4096;
constexpr int C = 128;
constexpr int T = 2048;
constexpr int W  = 16;    // window rows per t
constexpr int TT = 8;     // t-values per block
constexpr int LROWS = 40; // staged rows: [t0-16, t0+24) covers all windows for |shift| <= 8

__global__ __launch_bounds__(256) void ShiftingLayer_63247688401341_kernel(
        const float* __restrict__ inp,     // (B,S,C)
        const float* __restrict__ shift,   // (B,T)
        float* __restrict__ out)           // (B,T,C)
{
    const int b  = blockIdx.y;
    const int t0 = blockIdx.x * TT;
    const int r0 = t0 - 16;               // first staged row (may be <0; clamped on load)
    const int tid = threadIdx.x;

    __shared__ float tile[LROWS * C];     // 20 KB staged input rows
    __shared__ float wsh[TT][W];          // Gaussian weights
    __shared__ int   s0sh[TT];            // window start row per t

    // --- Phase 1a: weight table (first 128 threads) ---
    if (tid < TT * W) {
        const int tt = tid >> 4;          // 0..7
        const int j  = tid & (W - 1);     // 0..15
        const int t  = t0 + tt;
        const float sh = shift[(size_t)b * T + t];
        const int s0 = (int)floorf((float)t - sh) - (W / 2 - 1);
        const int s  = s0 + j;
        const float x = sh + (float)(s - t);
        float w = __expf(-4.0f * x * x);
        if (s < 0 || s >= S) w = 0.0f;    // OOB rows contribute 0
        wsh[tt][j] = w;
        if (j == 0) s0sh[tt] = s0;
    }

    // --- Phase 1b: stage 40 contiguous rows into LDS (coalesced stream) ---
    const float* bbase = inp + (size_t)b * S * C;
    #pragma unroll
    for (int k = 0; k < (LROWS * C / 4) / 256; ++k) {   // 1280 float4 / 256 thr = 5
        const int idx  = tid + k * 256;                 // float4 index in tile
        const int row  = idx >> 5;                      // /32 float4 per row
        const int col4 = (idx & 31) * 4;
        int srow = r0 + row;
        srow = srow < 0 ? 0 : (srow >= S ? S - 1 : srow);  // clamp; weight=0 there
        const float4 v = *(const float4*)(bbase + (size_t)srow * C + col4);
        *(float4*)(&tile[row * C + col4]) = v;
    }
    __syncthreads();

    // --- Block-uniform check: did every window land inside the staged range? ---
    bool allok = true;
    #pragma unroll
    for (int tt = 0; tt < TT; ++tt) {
        const int d = s0sh[tt] - r0;
        allok &= (d >= 0) && (d <= LROWS - W);
    }

    const int tt = tid >> 5;              // 0..7
    const int c4 = (tid & 31) * 4;        // channel group
    const int t  = t0 + tt;
    const int s0 = s0sh[tt];
    float4 acc = make_float4(0.f, 0.f, 0.f, 0.f);

    if (allok) {
        // --- Fast path: 16 taps from LDS ---
        const float* lrow = &tile[(s0 - r0) * C + c4];
        #pragma unroll
        for (int j = 0; j < W; ++j) {
            const float4 v = *(const float4*)(lrow + j * C);
            const float w = wsh[tt][j];
            acc.x = fmaf(w, v.x, acc.x);
            acc.y = fmaf(w, v.y, acc.y);
            acc.z = fmaf(w, v.z, acc.z);
            acc.w = fmaf(w, v.w, acc.w);
        }
    } else {
        // --- Fallback (|shift| > 8; never hit for N(0,1) inputs): global loads ---
        const float* base = bbase + c4;
        #pragma unroll
        for (int j = 0; j < W; ++j) {
            int srow = s0 + j;
            srow = srow < 0 ? 0 : (srow >= S ? S - 1 : srow);
            const float4 v = *(const float4*)(base + (size_t)srow * C);
            const float w = wsh[tt][j];
            acc.x = fmaf(w, v.x, acc.x);
            acc.y = fmaf(w, v.y, acc.y);
            acc.z = fmaf(w, v.z, acc.z);
            acc.w = fmaf(w, v.w, acc.w);
        }
    }
    *(float4*)(out + ((size_t)b * T + t) * C + c4) = acc;
}

extern "C" void kernel_launch(void* const* d_in, const int* in_sizes, int n_in,
                              void* d_out, int out_size, void* d_ws, size_t ws_size,
                              hipStream_t stream) {
    const float* inp   = (const float*)d_in[0];
    const float* shift = (const float*)d_in[1];
    float* out = (float*)d_out;

    dim3 grid(T / TT, B);   // (256, 16)
    dim3 block(256);
    ShiftingLayer_63247688401341_kernel<<<grid, block, 0, stream>>>(inp, shift, out);
}

// Round 4
// 79.779 us; speedup vs baseline: 1.0847x; 1.0847x over previous
//
#include <hip/hip_runtime.h>

// input: (B=16, S=4096, C=128) fp32; shift: (B=16, T=2048) fp32
// out[b,t,c] = sum_s exp(-4*(shift[b,t]+s-t)^2) * input[b,s,c]
// Tap weight at |x|>=3.5 is exp(-49)=5e-22 => an 8-wide window centered at
// t-shift is exact to fp32 (truncation ~1e-15, threshold 9.6e-2).
constexpr int B = 16;
constexpr int S = 4096;
constexpr int C = 128;
constexpr int T = 2048;
constexpr int W  = 8;      // taps per t: s in [floor(t-sh)-3, floor(t-sh)+4]
constexpr int TT = 16;     // t-values per block
constexpr int PRE = 8;     // staged range starts at t0-PRE
constexpr int LROWS = 32;  // staged rows [t0-8, t0+24): covers |shift| <= ~5

__global__ __launch_bounds__(256, 6) void ShiftingLayer_63247688401341_kernel(
        const float* __restrict__ inp,     // (B,S,C)
        const float* __restrict__ shift,   // (B,T)
        float* __restrict__ out)           // (B,T,C)
{
    const int b   = blockIdx.y;
    const int t0  = blockIdx.x * TT;
    const int r0  = t0 - PRE;
    const int tid = threadIdx.x;

    __shared__ __align__(16) float tile[LROWS * C];  // 16 KB staged rows
    __shared__ __align__(16) float wsh[TT][W];       // 512 B weights
    __shared__ int s0sh[TT];

    // --- Weight table: threads 0..127, one (t, tap) each ---
    if (tid < TT * W) {
        const int tt = tid >> 3;          // 0..15
        const int j  = tid & (W - 1);     // 0..7
        const int t  = t0 + tt;
        const float sh = shift[b * T + t];
        const int s0 = (int)floorf((float)t - sh) - (W / 2 - 1);
        const int s  = s0 + j;
        const float x = sh + (float)(s - t);
        float w = __expf(-4.0f * x * x);
        if (s < 0 || s >= S) w = 0.0f;    // OOB rows contribute 0
        wsh[tt][j] = w;
        if (j == 0) s0sh[tt] = s0;
    }

    // --- Stage 32 rows via async global->LDS DMA (no VGPR round-trip).
    // Per-lane gptr (row-clamped) is fine; LDS dest is wave-uniform base
    // + lane*16, which matches the linear idx4 layout exactly.
    const float* bbase = inp + (size_t)b * S * C;
    const int wave = tid >> 6, lane = tid & 63;
    #pragma unroll
    for (int k = 0; k < (LROWS * C / 4) / 256; ++k) {   // 4 iters
        const int base4 = k * 256 + wave * 64;          // wave-uniform float4 slot
        const int idx4  = base4 + lane;
        const int row   = idx4 >> 5;                    // 32 float4 per row
        const int col4  = (idx4 & 31) << 2;
        int srow = r0 + row;
        srow = srow < 0 ? 0 : (srow >= S ? S - 1 : srow);  // weight=0 there anyway
        const float* g = bbase + (size_t)srow * C + col4;
        __builtin_amdgcn_global_load_lds(
            (const __attribute__((address_space(1))) void*)g,
            (__attribute__((address_space(3))) void*)(&tile[base4 * 4]),
            16, 0, 0);
    }
    __syncthreads();

    // --- Compute: each thread owns (c4, {tt, tt+8}) ---
    const int c4 = (tid & 31) << 2;
    const int ttb = tid >> 5;             // 0..7
    #pragma unroll
    for (int h = 0; h < 2; ++h) {
        const int tt = ttb + h * 8;
        const int t  = t0 + tt;
        const int s0 = s0sh[tt];
        const int d  = s0 - r0;

        float wv[W];
        *(float4*)(&wv[0]) = *(const float4*)(&wsh[tt][0]);
        *(float4*)(&wv[4]) = *(const float4*)(&wsh[tt][4]);

        float4 acc = make_float4(0.f, 0.f, 0.f, 0.f);
        if (d >= 0 && d <= LROWS - W) {
            // Fast path: 8 taps from LDS (b128, conflict-free)
            const float* lrow = &tile[d * C + c4];
            #pragma unroll
            for (int j = 0; j < W; ++j) {
                const float4 v = *(const float4*)(lrow + j * C);
                acc.x = fmaf(wv[j], v.x, acc.x);
                acc.y = fmaf(wv[j], v.y, acc.y);
                acc.z = fmaf(wv[j], v.z, acc.z);
                acc.w = fmaf(wv[j], v.w, acc.w);
            }
        } else {
            // Fallback (|shift| > ~5; ~never for N(0,1)): global loads
            #pragma unroll
            for (int j = 0; j < W; ++j) {
                int srow = s0 + j;
                srow = srow < 0 ? 0 : (srow >= S ? S - 1 : srow);
                const float4 v = *(const float4*)(bbase + (size_t)srow * C + c4);
                acc.x = fmaf(wv[j], v.x, acc.x);
                acc.y = fmaf(wv[j], v.y, acc.y);
                acc.z = fmaf(wv[j], v.z, acc.z);
                acc.w = fmaf(wv[j], v.w, acc.w);
            }
        }
        *(float4*)(out + ((size_t)b * T + t) * C + c4) = acc;
    }
}

extern "C" void kernel_launch(void* const* d_in, const int* in_sizes, int n_in,
                              void* d_out, int out_size, void* d_ws, size_t ws_size,
                              hipStream_t stream) {
    const float* inp   = (const float*)d_in[0];
    const float* shift = (const float*)d_in[1];
    float* out = (float*)d_out;

    dim3 grid(T / TT, B);   // (128, 16) = 2048 blocks
    dim3 block(256);
    ShiftingLayer_63247688401341_kernel<<<grid, block, 0, stream>>>(inp, shift, out);
}

// Round 5
// 79.065 us; speedup vs baseline: 1.0945x; 1.0090x over previous
//
#include <hip/hip_runtime.h>

// input: (B=16, S=4096, C=128) fp32; shift: (B=16, T=2048) fp32
// out[b,t,c] = sum_s exp(-4*(shift[b,t]+s-t)^2) * input[b,s,c]
// W=4 taps centered on floor(t-shift): worst truncated tap has |x|>=2 =>
// weight <= exp(-16)=1.1e-7; total truncation ~1e-6 (threshold 9.6e-2).
constexpr int B = 16;
constexpr int S = 4096;
constexpr int C = 128;
constexpr int T = 2048;
constexpr int W  = 4;      // taps per t: s in [floor(t-sh)-1, floor(t-sh)+2]
constexpr int TT = 32;     // t-values per block -> 1024 blocks = 4/CU, all resident
constexpr int PRE = 8;     // staged range starts at t0-PRE
constexpr int LROWS = 48;  // staged rows [t0-8, t0+40): covers |shift| <= ~6

__global__ __launch_bounds__(256, 4) void ShiftingLayer_63247688401341_kernel(
        const float* __restrict__ inp,     // (B,S,C)
        const float* __restrict__ shift,   // (B,T)
        float* __restrict__ out)           // (B,T,C)
{
    const int b   = blockIdx.y;
    const int t0  = blockIdx.x * TT;
    const int r0  = t0 - PRE;
    const int tid = threadIdx.x;

    __shared__ __align__(16) float tile[LROWS * C];  // 24.6 KB staged rows
    __shared__ __align__(16) float wsh[TT][W];       // 512 B weights (float4/t)
    __shared__ int s0sh[TT];

    // --- Weight table: threads 0..127, one (t, tap) each ---
    if (tid < TT * W) {
        const int tt = tid >> 2;          // 0..31
        const int j  = tid & (W - 1);     // 0..3
        const int t  = t0 + tt;
        const float sh = shift[b * T + t];
        const int s0 = (int)floorf((float)t - sh) - (W / 2 - 1);
        const int s  = s0 + j;
        const float x = sh + (float)(s - t);
        float w = __expf(-4.0f * x * x);
        if (s < 0 || s >= S) w = 0.0f;    // OOB rows contribute 0
        wsh[tt][j] = w;
        if (j == 0) s0sh[tt] = s0;
    }

    // --- Stage 48 rows via async global->LDS DMA (wave-uniform base + lane*16) ---
    const float* bbase = inp + (size_t)b * S * C;
    const int wave = tid >> 6, lane = tid & 63;
    #pragma unroll
    for (int k = 0; k < (LROWS * C / 4) / 256; ++k) {   // 6 iters
        const int base4 = k * 256 + wave * 64;          // wave-uniform float4 slot
        const int idx4  = base4 + lane;
        const int row   = idx4 >> 5;                    // 32 float4 per row
        const int col4  = (idx4 & 31) << 2;
        int srow = r0 + row;
        srow = srow < 0 ? 0 : (srow >= S ? S - 1 : srow);  // weight=0 there anyway
        const float* g = bbase + (size_t)srow * C + col4;
        __builtin_amdgcn_global_load_lds(
            (const __attribute__((address_space(1))) void*)g,
            (__attribute__((address_space(3))) void*)(&tile[base4 * 4]),
            16, 0, 0);
    }
    __syncthreads();

    // --- Compute: thread owns (c4 = (tid&31)*4, t's {ttb, ttb+8, ttb+16, ttb+24}) ---
    const int c4  = (tid & 31) << 2;
    const int ttb = tid >> 5;             // 0..7
    #pragma unroll
    for (int h = 0; h < 4; ++h) {
        const int tt = ttb + h * 8;
        const int t  = t0 + tt;
        const int s0 = s0sh[tt];
        const int d  = s0 - r0;
        const float4 w = *(const float4*)(&wsh[tt][0]);

        float4 acc = make_float4(0.f, 0.f, 0.f, 0.f);
        if (d >= 0 && d <= LROWS - W) {
            // Fast path: 4 taps from LDS (b128, conflict-free)
            const float* lrow = &tile[d * C + c4];
            const float4 v0 = *(const float4*)(lrow);
            const float4 v1 = *(const float4*)(lrow + C);
            const float4 v2 = *(const float4*)(lrow + 2 * C);
            const float4 v3 = *(const float4*)(lrow + 3 * C);
            acc.x = fmaf(w.x, v0.x, fmaf(w.y, v1.x, fmaf(w.z, v2.x, w.w * v3.x)));
            acc.y = fmaf(w.x, v0.y, fmaf(w.y, v1.y, fmaf(w.z, v2.y, w.w * v3.y)));
            acc.z = fmaf(w.x, v0.z, fmaf(w.y, v1.z, fmaf(w.z, v2.z, w.w * v3.z)));
            acc.w = fmaf(w.x, v0.w, fmaf(w.y, v1.w, fmaf(w.z, v2.w, w.w * v3.w)));
        } else {
            // Fallback (|shift| > ~6; ~never for N(0,1)): global loads
            const float wv[W] = {w.x, w.y, w.z, w.w};
            #pragma unroll
            for (int j = 0; j < W; ++j) {
                int srow = s0 + j;
                srow = srow < 0 ? 0 : (srow >= S ? S - 1 : srow);
                const float4 v = *(const float4*)(bbase + (size_t)srow * C + c4);
                acc.x = fmaf(wv[j], v.x, acc.x);
                acc.y = fmaf(wv[j], v.y, acc.y);
                acc.z = fmaf(wv[j], v.z, acc.z);
                acc.w = fmaf(wv[j], v.w, acc.w);
            }
        }
        *(float4*)(out + ((size_t)b * T + t) * C + c4) = acc;
    }
}

extern "C" void kernel_launch(void* const* d_in, const int* in_sizes, int n_in,
                              void* d_out, int out_size, void* d_ws, size_t ws_size,
                              hipStream_t stream) {
    const float* inp   = (const float*)d_in[0];
    const float* shift = (const float*)d_in[1];
    float* out = (float*)d_out;

    dim3 grid(T / TT, B);   // (64, 16) = 1024 blocks = 4 per CU (all resident)
    dim3 block(256);
    ShiftingLayer_63247688401341_kernel<<<grid, block, 0, stream>>>(inp, shift, out);
}

// Round 6
// 76.890 us; speedup vs baseline: 1.1255x; 1.0283x over previous
//
#include <hip/hip_runtime.h>

// input: (B=16, S=4096, C=128) fp32; shift: (B=16, T=2048) fp32
// out[b,t,c] = sum_s exp(-4*(shift[b,t]+s-t)^2) * input[b,s,c]
// W=4 taps centered on floor(t-shift): worst truncated tap has |x|>=2 =>
// weight <= exp(-16)=1.1e-7; truncation ~1e-6 (threshold 9.6e-2).
// A block's tap footprint (~42 rows x 512 B ~= 21.5 KB) fits L1, so taps
// load straight from global (L1-resident) -- no LDS tile, no DMA barrier.
constexpr int B = 16;
constexpr int S = 4096;
constexpr int C = 128;
constexpr int T = 2048;
constexpr int W  = 4;      // taps per t
constexpr int TT = 32;     // t-values per block -> 1024 blocks = 4/CU

__global__ __launch_bounds__(256, 4) void ShiftingLayer_63247688401341_kernel(
        const float* __restrict__ inp,     // (B,S,C)
        const float* __restrict__ shift,   // (B,T)
        float* __restrict__ out)           // (B,T,C)
{
    const int b   = blockIdx.y;
    const int t0  = blockIdx.x * TT;
    const int tid = threadIdx.x;

    __shared__ __align__(16) float wsh[TT][W];   // 512 B weight table
    __shared__ int s0sh[TT];

    // --- Weight table: threads 0..127, one (t, tap) each. OOB taps get w=0. ---
    if (tid < TT * W) {
        const int tt = tid >> 2;          // 0..31
        const int j  = tid & (W - 1);     // 0..3
        const int t  = t0 + tt;
        const float sh = shift[b * T + t];
        const int s0 = (int)floorf((float)t - sh) - (W / 2 - 1);
        const int s  = s0 + j;
        const float x = sh + (float)(s - t);
        float w = __expf(-4.0f * x * x);
        if (s < 0 || s >= S) w = 0.0f;
        wsh[tt][j] = w;
        if (j == 0) s0sh[tt] = s0;
    }
    __syncthreads();   // waits only on 132 LDS dwords (cheap)

    // --- Compute: thread owns (c4 = (tid&31)*4, t's {ttb, ttb+8, ttb+16, ttb+24}).
    // 16 independent clamped-row float4 loads in flight; all L1-resident.
    const int c4  = (tid & 31) << 2;
    const int ttb = tid >> 5;             // 0..7
    const float* bbase = inp + (size_t)b * S * C + c4;

    #pragma unroll
    for (int h = 0; h < 4; ++h) {
        const int tt = ttb + h * 8;
        const int t  = t0 + tt;
        const int s0 = s0sh[tt];
        const float4 w = *(const float4*)(&wsh[tt][0]);

        int r0s = s0,     r1s = s0 + 1, r2s = s0 + 2, r3s = s0 + 3;
        r0s = r0s < 0 ? 0 : (r0s >= S ? S - 1 : r0s);
        r1s = r1s < 0 ? 0 : (r1s >= S ? S - 1 : r1s);
        r2s = r2s < 0 ? 0 : (r2s >= S ? S - 1 : r2s);
        r3s = r3s < 0 ? 0 : (r3s >= S ? S - 1 : r3s);

        const float4 v0 = *(const float4*)(bbase + (size_t)r0s * C);
        const float4 v1 = *(const float4*)(bbase + (size_t)r1s * C);
        const float4 v2 = *(const float4*)(bbase + (size_t)r2s * C);
        const float4 v3 = *(const float4*)(bbase + (size_t)r3s * C);

        float4 acc;
        acc.x = fmaf(w.x, v0.x, fmaf(w.y, v1.x, fmaf(w.z, v2.x, w.w * v3.x)));
        acc.y = fmaf(w.x, v0.y, fmaf(w.y, v1.y, fmaf(w.z, v2.y, w.w * v3.y)));
        acc.z = fmaf(w.x, v0.z, fmaf(w.y, v1.z, fmaf(w.z, v2.z, w.w * v3.z)));
        acc.w = fmaf(w.x, v0.w, fmaf(w.y, v1.w, fmaf(w.z, v2.w, w.w * v3.w)));

        *(float4*)(out + ((size_t)b * T + t) * C + c4) = acc;
    }
}

extern "C" void kernel_launch(void* const* d_in, const int* in_sizes, int n_in,
                              void* d_out, int out_size, void* d_ws, size_t ws_size,
                              hipStream_t stream) {
    const float* inp   = (const float*)d_in[0];
    const float* shift = (const float*)d_in[1];
    float* out = (float*)d_out;

    dim3 grid(T / TT, B);   // (64, 16) = 1024 blocks = 4 per CU
    dim3 block(256);
    ShiftingLayer_63247688401341_kernel<<<grid, block, 0, stream>>>(inp, shift, out);
}

// Round 7
// 76.504 us; speedup vs baseline: 1.1312x; 1.0050x over previous
//
#include <hip/hip_runtime.h>

// input: (B=16, S=4096, C=128) fp32; shift: (B=16, T=2048) fp32
// out[b,t,c] = sum_s exp(-4*(shift[b,t]+s-t)^2) * input[b,s,c]
// W=4 taps centered on floor(t-shift): worst truncated tap has |x|>=2 =>
// weight <= exp(-16)=1.1e-7; truncation ~1e-6 (threshold 9.6e-2).
// Tap footprint per block (~42 rows x 512 B) is L1-resident: taps load
// straight from global. Output stored nontemporally (never re-read).
constexpr int B = 16;
constexpr int S = 4096;
constexpr int C = 128;
constexpr int T = 2048;
constexpr int W  = 4;      // taps per t
constexpr int TT = 32;     // t-values per block -> 1024 blocks = 4/CU

typedef float v4f __attribute__((ext_vector_type(4)));

__global__ __launch_bounds__(256, 4) void ShiftingLayer_63247688401341_kernel(
        const float* __restrict__ inp,     // (B,S,C)
        const float* __restrict__ shift,   // (B,T)
        float* __restrict__ out)           // (B,T,C)
{
    const int b   = blockIdx.y;
    const int t0  = blockIdx.x * TT;
    const int tid = threadIdx.x;

    __shared__ __align__(16) float wsh[TT][W];   // 512 B weight table
    __shared__ int s0sh[TT];

    // --- Weight table: threads 0..127, one (t, tap) each. OOB taps get w=0. ---
    if (tid < TT * W) {
        const int tt = tid >> 2;          // 0..31
        const int j  = tid & (W - 1);     // 0..3
        const int t  = t0 + tt;
        const float sh = shift[b * T + t];
        const int s0 = (int)floorf((float)t - sh) - (W / 2 - 1);
        const int s  = s0 + j;
        const float x = sh + (float)(s - t);
        float w = __expf(-4.0f * x * x);
        if (s < 0 || s >= S) w = 0.0f;
        wsh[tt][j] = w;
        if (j == 0) s0sh[tt] = s0;
    }
    __syncthreads();   // waits only on 132 LDS dwords (cheap)

    // --- Compute: thread owns (c4 = (tid&31)*4, t's {ttb, ttb+8, ttb+16, ttb+24}).
    // 16 independent clamped-row float4 loads in flight; all L1-resident.
    const int c4  = (tid & 31) << 2;
    const int ttb = tid >> 5;             // 0..7
    const float* bbase = inp + (size_t)b * S * C + c4;
    float* obase = out + ((size_t)b * T + t0) * C + c4;

    #pragma unroll
    for (int h = 0; h < 4; ++h) {
        const int tt = ttb + h * 8;
        const int s0 = s0sh[tt];
        const float4 w = *(const float4*)(&wsh[tt][0]);

        int r0s = s0,     r1s = s0 + 1, r2s = s0 + 2, r3s = s0 + 3;
        r0s = r0s < 0 ? 0 : (r0s >= S ? S - 1 : r0s);
        r1s = r1s < 0 ? 0 : (r1s >= S ? S - 1 : r1s);
        r2s = r2s < 0 ? 0 : (r2s >= S ? S - 1 : r2s);
        r3s = r3s < 0 ? 0 : (r3s >= S ? S - 1 : r3s);

        const float4 v0 = *(const float4*)(bbase + (size_t)r0s * C);
        const float4 v1 = *(const float4*)(bbase + (size_t)r1s * C);
        const float4 v2 = *(const float4*)(bbase + (size_t)r2s * C);
        const float4 v3 = *(const float4*)(bbase + (size_t)r3s * C);

        v4f acc;
        acc.x = fmaf(w.x, v0.x, fmaf(w.y, v1.x, fmaf(w.z, v2.x, w.w * v3.x)));
        acc.y = fmaf(w.x, v0.y, fmaf(w.y, v1.y, fmaf(w.z, v2.y, w.w * v3.y)));
        acc.z = fmaf(w.x, v0.z, fmaf(w.y, v1.z, fmaf(w.z, v2.z, w.w * v3.z)));
        acc.w = fmaf(w.x, v0.w, fmaf(w.y, v1.w, fmaf(w.z, v2.w, w.w * v3.w)));

        // Nontemporal: output is write-once, never re-read -> don't pollute L1/L2.
        __builtin_nontemporal_store(acc, (v4f*)(obase + (size_t)tt * C));
    }
}

extern "C" void kernel_launch(void* const* d_in, const int* in_sizes, int n_in,
                              void* d_out, int out_size, void* d_ws, size_t ws_size,
                              hipStream_t stream) {
    const float* inp   = (const float*)d_in[0];
    const float* shift = (const float*)d_in[1];
    float* out = (float*)d_out;

    dim3 grid(T / TT, B);   // (64, 16) = 1024 blocks = 4 per CU
    dim3 block(256);
    ShiftingLayer_63247688401341_kernel<<<grid, block, 0, stream>>>(inp, shift, out);
}